// Round 13
// baseline (238.458 us; speedup 1.0000x reference)
//
#include <hip/hip_runtime.h>
#include <stdint.h>

#define NB 16
#define LQ 2048
#define LK 2048
#define DH 64
#define QT 16
#define NW 16
#define STRIP 256            // NW*16 keys per ph1 iteration
#define NIT 8                // LK/STRIP
#define TPB 8                // q-tiles per block

typedef short bf16x8 __attribute__((ext_vector_type(8)));
typedef float f32x4 __attribute__((ext_vector_type(4)));

__device__ __forceinline__ unsigned short f2bf(float f) {
    union { float f; uint32_t u; } v; v.f = f;
    uint32_t u = v.u;
    u += 0x7FFFu + ((u >> 16) & 1u);
    return (unsigned short)(u >> 16);
}
__device__ __forceinline__ float bf2f(unsigned short h) {
    union { uint32_t u; float f; } v; v.u = ((uint32_t)h) << 16;
    return v.f;
}
__device__ __forceinline__ uint32_t pack2(float lo, float hi) {
    return (uint32_t)f2bf(lo) | ((uint32_t)f2bf(hi) << 16);
}

// ---------------- pre-pass: f32 -> bf16 (Q, K) and f32 -> bf16 transposed (V) ----
__global__ void convert_kernel(const float* __restrict__ q, const float* __restrict__ k,
                               const float* __restrict__ v,
                               unsigned short* __restrict__ qb,
                               unsigned short* __restrict__ kb,
                               unsigned short* __restrict__ vtb) {
    int bid = blockIdx.x;
    int tid = threadIdx.x;
    if (bid < 2048) {
        const float* src = (bid < 1024) ? q : k;
        unsigned short* dst = (bid < 1024) ? qb : kb;
        int64_t off = (int64_t)(bid & 1023) * 2048 + (int64_t)tid * 8;
        float4 a = *(const float4*)(src + off);
        float4 b4 = *(const float4*)(src + off + 4);
        uint4 o;
        o.x = pack2(a.x, a.y);
        o.y = pack2(a.z, a.w);
        o.z = pack2(b4.x, b4.y);
        o.w = pack2(b4.z, b4.w);
        *(uint4*)(dst + off) = o;
    } else {
        __shared__ unsigned short tile[64][72];
        int bid2 = bid - 2048;
        int bb = bid2 >> 5, kt = bid2 & 31;
        int k0 = kt * 64;
        int krow = tid >> 2, dc = (tid & 3) * 16;
        const float* vp = v + ((int64_t)(bb * LK) + k0 + krow) * DH + dc;
        float4 x0 = *(const float4*)(vp);
        float4 x1 = *(const float4*)(vp + 4);
        float4 x2 = *(const float4*)(vp + 8);
        float4 x3 = *(const float4*)(vp + 12);
        float vals[16] = {x0.x, x0.y, x0.z, x0.w, x1.x, x1.y, x1.z, x1.w,
                          x2.x, x2.y, x2.z, x2.w, x3.x, x3.y, x3.z, x3.w};
        #pragma unroll
        for (int i = 0; i < 16; ++i) tile[dc + i][krow] = f2bf(vals[i]);
        __syncthreads();
        int d = tid >> 2, kc = (tid & 3) * 16;
        uint4 r0 = *(const uint4*)&tile[d][kc];
        uint4 r1 = *(const uint4*)&tile[d][kc + 8];
        unsigned short* op = vtb + ((int64_t)(bb * DH) + d) * LK + k0 + kc;
        *(uint4*)op = r0;
        *(uint4*)(op + 8) = r1;
    }
}

__device__ __forceinline__ void ld_f32x4(f32x4& d, const float* p) {
    asm volatile("global_load_dwordx4 %0, %1, off" : "=v"(d) : "v"((uint64_t)p));
}

// ---------------- fused attention: 1 block/CU, true stream||compute pipeline -----
// grid 256, 1024 threads (16 waves). LDS: e dbuf 2x65536 + den[2][16] 128 +
// pp[12][16][16] 12288 = 143488 B -> 1 block/CU.
// Per iteration: Region A = {issue mask(i+1) loads, attn(i) stores, PV(i), out(i),
// ph1(i+1)} -- HBM streams ride under compute. Region B = mconsume only (LDS/VALU).
__launch_bounds__(1024, 4)
__global__ void attn_kernel(const unsigned short* __restrict__ qb,
                            const unsigned short* __restrict__ kb,
                            const unsigned short* __restrict__ vtb,
                            const float* __restrict__ mask,
                            float* __restrict__ out, float* __restrict__ attn) {
    extern __shared__ char smem[];
    float* denb = (float*)(smem + 131072);           // [2][16]
    float* pp   = (float*)(smem + 131072 + 128);     // [12][16][16]

    int bid = blockIdx.x;
    int b  = (bid & 7) * 2 + (bid >> 7);   // 2 batches per XCD -> K/V L2-resident
    int qc = (bid >> 3) & 15;              // q-chunk: 8 tiles

    int tid = threadIdx.x;
    int lane = tid & 63, wave = tid >> 6;
    int lr = lane & 15, lg = lane >> 4;

    const int64_t brow = (int64_t)b * LQ;
    const unsigned short* kpw =
        kb + (int64_t)b * LK * DH + (wave * 16 + lr) * DH + 8 * lg;

    f32x4 mk[8];   // in-flight mask stage (wave-per-row, contiguous 1KB bursts)

    auto mload_issue = [&](int q0) {      // asm: issue 8 loads, do NOT wait
        const float* mrow = mask + (brow + q0 + wave) * LK;
        int c0l = lane * 8;
        #pragma unroll
        for (int i = 0; i < 4; ++i) {
            ld_f32x4(mk[2 * i],     mrow + i * 512 + c0l);
            ld_f32x4(mk[2 * i + 1], mrow + i * 512 + c0l + 4);
        }
        __builtin_amdgcn_sched_barrier(0);
    };
    auto mwait = [&]() {
        asm volatile("s_waitcnt vmcnt(0)"
                     : "+v"(mk[0]), "+v"(mk[1]), "+v"(mk[2]), "+v"(mk[3]),
                       "+v"(mk[4]), "+v"(mk[5]), "+v"(mk[6]), "+v"(mk[7]));
        __builtin_amdgcn_sched_barrier(0);
    };

    // ---- ph1: unmasked p = exp(clamp(QK^T/8)) -> ebuf (K/Q from L2) ----
    auto ph1 = [&](int q0, char* ebuf) {
        const unsigned short* qp = qb + (brow + q0 + lr) * DH + 8 * lg;
        bf16x8 qf0 = *(const bf16x8*)qp;
        bf16x8 qf1 = *(const bf16x8*)(qp + 32);
        bf16x8 kf0 = *(const bf16x8*)kpw;
        bf16x8 kf1 = *(const bf16x8*)(kpw + 32);
        #pragma unroll
        for (int kt = 0; kt < NIT; ++kt) {
            bf16x8 nk0, nk1;
            if (kt + 1 < NIT) {
                const unsigned short* np = kpw + (int64_t)(kt + 1) * STRIP * DH;
                nk0 = *(const bf16x8*)np;
                nk1 = *(const bf16x8*)(np + 32);
            }
            f32x4 acc = {0.f, 0.f, 0.f, 0.f};
            acc = __builtin_amdgcn_mfma_f32_16x16x32_bf16(kf0, qf0, acc, 0, 0, 0);
            acc = __builtin_amdgcn_mfma_f32_16x16x32_bf16(kf1, qf1, acc, 0, 0, 0);
            unsigned short eb[4];
            #pragma unroll
            for (int j = 0; j < 4; ++j) {
                float sc = acc[j] * 0.125f;
                sc = fminf(fmaxf(sc, -15.0f), 15.0f);
                eb[j] = f2bf(__expf(sc));
            }
            uint2 u;
            u.x = (uint32_t)eb[0] | ((uint32_t)eb[1] << 16);
            u.y = (uint32_t)eb[2] | ((uint32_t)eb[3] << 16);
            int c = kt * STRIP + wave * 16 + lg * 4;
            int byteoff = (lr * 4096 + c * 2) ^ ((lr & 7) << 4);
            *(uint2*)(ebuf + byteoff) = u;
            kf0 = nk0; kf1 = nk1;
        }
    };

    auto mconsume = [&](char* ebuf, int par) {
        int r = wave;
        int rowbase = r * 4096, sw = (r & 7) << 4;
        int c0l = lane * 8;
        float dsum = 0.f;
        #pragma unroll
        for (int i = 0; i < 4; ++i) {
            int byteoff = (rowbase + (i * 512 + c0l) * 2) ^ sw;
            bf16x8 pv = *(const bf16x8*)(ebuf + byteoff);
            uint32_t packed[4];
            #pragma unroll
            for (int h = 0; h < 4; ++h) {
                float m0 = (h < 2) ? mk[2 * i][2 * h] : mk[2 * i + 1][2 * h - 4];
                float m1 = (h < 2) ? mk[2 * i][2 * h + 1] : mk[2 * i + 1][2 * h - 3];
                unsigned short e0 = (m0 != 0.f) ? (unsigned short)pv[2 * h] : (unsigned short)0;
                unsigned short e1 = (m1 != 0.f) ? (unsigned short)pv[2 * h + 1] : (unsigned short)0;
                dsum += bf2f(e0) + bf2f(e1);
                packed[h] = (uint32_t)e0 | ((uint32_t)e1 << 16);
            }
            uint4 wb = {packed[0], packed[1], packed[2], packed[3]};
            *(uint4*)(ebuf + byteoff) = wb;
        }
        dsum += __shfl_xor(dsum, 1);
        dsum += __shfl_xor(dsum, 2);
        dsum += __shfl_xor(dsum, 4);
        dsum += __shfl_xor(dsum, 8);
        dsum += __shfl_xor(dsum, 16);
        dsum += __shfl_xor(dsum, 32);
        if (lane == 0) denb[par * 16 + r] = dsum + 1e-6f;
    };

    auto atw = [&](int q0, char* ebuf, int par) {
        int r = wave;
        float inv = 1.0f / denb[par * 16 + r];
        float* ap = attn + (brow + q0 + r) * LK;
        int rowbase = r * 4096, sw = (r & 7) << 4;
        int c0l = lane * 8;
        #pragma unroll
        for (int i = 0; i < 4; ++i) {
            int byteoff = (rowbase + (i * 512 + c0l) * 2) ^ sw;
            bf16x8 ev = *(const bf16x8*)(ebuf + byteoff);
            f32x4 o0, o1;
            o0[0] = bf2f((unsigned short)ev[0]) * inv;
            o0[1] = bf2f((unsigned short)ev[1]) * inv;
            o0[2] = bf2f((unsigned short)ev[2]) * inv;
            o0[3] = bf2f((unsigned short)ev[3]) * inv;
            o1[0] = bf2f((unsigned short)ev[4]) * inv;
            o1[1] = bf2f((unsigned short)ev[5]) * inv;
            o1[2] = bf2f((unsigned short)ev[6]) * inv;
            o1[3] = bf2f((unsigned short)ev[7]) * inv;
            *(f32x4*)(ap + i * 512 + c0l) = o0;
            *(f32x4*)(ap + i * 512 + c0l + 4) = o1;
        }
    };

    char* eb0 = smem;
    char* eb1 = smem + 65536;

    // ---- prologue: tile 0 (mask stream rides under ph1 compute) ----
    {
        int q0 = (qc * TPB) * QT;
        mload_issue(q0);
        ph1(q0, eb0);
        __syncthreads();
        mwait();
        mconsume(eb0, 0);
        __syncthreads();
    }

    // ---- pipelined main loop ----
    for (int i = 0; i < TPB; ++i) {
        int par = i & 1;
        char* ebuf = par ? eb1 : eb0;
        char* nbuf = par ? eb0 : eb1;
        int q0  = (qc * TPB + i) * QT;
        int q0n = (qc * TPB + i + 1) * QT;

        // ===== REGION A: issue mask(i+1) || attn-store(i) || PV(i)+out(i) || ph1(i+1)
        if (i + 1 < TPB) mload_issue(q0n);
        atw(q0, ebuf, par);                 // stores fire-and-forget, drain under compute

        f32x4 pacc = {0.f, 0.f, 0.f, 0.f};
        int cw = (wave & 3) * 16, kq = wave >> 2;
        {
            const unsigned short* vp =
                vtb + ((int64_t)(b * DH + cw + lr)) * LK + kq * 512 + 8 * lg;
            int rowbase = lr * 4096;
            int sw = (lr & 7) << 4;
            int kk0 = kq * 512;
            #pragma unroll 4
            for (int kk = 0; kk < 512; kk += 32) {
                int byteoff = (rowbase + (kk0 + kk + 8 * lg) * 2) ^ sw;
                bf16x8 ef = *(const bf16x8*)(ebuf + byteoff);
                bf16x8 vf = *(const bf16x8*)(vp + kk);
                pacc = __builtin_amdgcn_mfma_f32_16x16x32_bf16(ef, vf, pacc, 0, 0, 0);
            }
        }
        if (kq != 0) {
            #pragma unroll
            for (int j = 0; j < 4; ++j)
                pp[((kq - 1) * 4 + (wave & 3)) * 256 + (lg * 4 + j) * 16 + lr] = pacc[j];
        }
        __syncthreads();   // bar A
        if (kq == 0) {
            int c4 = wave & 3;
            #pragma unroll
            for (int j = 0; j < 4; ++j) {
                int r = lg * 4 + j;
                float dd = denb[par * 16 + r];
                float val = pacc[j] + pp[(c4) * 256 + r * 16 + lr] +
                            pp[(4 + c4) * 256 + r * 16 + lr] +
                            pp[(8 + c4) * 256 + r * 16 + lr];
                out[(brow + q0 + r) * DH + cw + lr] = val / dd;
            }
        }
        if (i + 1 < TPB) ph1(q0n, nbuf);
        __syncthreads();   // bar B

        // ===== REGION B: mconsume(i+1) only (LDS/VALU; masks arrived long ago) ====
        if (i + 1 < TPB) {
            mwait();
            mconsume(nbuf, par ^ 1);
        }
        __syncthreads();   // bar C
    }
}

extern "C" void kernel_launch(void* const* d_in, const int* in_sizes, int n_in,
                              void* d_out, int out_size, void* d_ws, size_t ws_size,
                              hipStream_t stream) {
    const float* q    = (const float*)d_in[0];
    const float* k    = (const float*)d_in[1];
    const float* v    = (const float*)d_in[2];
    const float* mask = (const float*)d_in[3];
    float* out  = (float*)d_out;
    float* attn = out + (int64_t)NB * LQ * DH;

    unsigned short* qb  = (unsigned short*)d_ws;
    unsigned short* kb  = qb + (int64_t)NB * LQ * DH;
    unsigned short* vtb = kb + (int64_t)NB * LK * DH;

    (void)hipFuncSetAttribute((const void*)attn_kernel,
                              hipFuncAttributeMaxDynamicSharedMemorySize, 143488);

    convert_kernel<<<2560, 256, 0, stream>>>(q, k, v, qb, kb, vtb);
    attn_kernel<<<256, 1024, 143488, stream>>>(qb, kb, vtb, mask, out, attn);
}